// Round 11
// baseline (461.474 us; speedup 1.0000x reference)
//
#include <hip/hip_runtime.h>
#include <hip/hip_bf16.h>

// LlamaAttention_49392123904401 — per-token head-mixing "attention".
// fp32 inputs (runtime-detected), bf16 MFMA compute, output in input dtype.
// Round 11: faithful m201-style 4-phase-per-K-tile schedule.
//  - per phase: {ds_read quadrant subtile, stage 1 half-tile (2 gloads),
//    barrier, lgkmcnt(0), setprio, 16 MFMA, setprio, barrier}
//  - stage stream offset 5: half u=5+4t+p staged at phase (t,p); every load
//    has >=4 phases (~2800cyc) before its consuming gate (>900cyc HBM).
//  - vmcnt(2) once per tile at p3 BEFORE the trailing barrier (cross-wave
//    visibility: vmcnt -> barrier -> reads). Tail: vmcnt(0) at t=14.
//  - B fragments persist in registers across phases: 24 b128/tile minimum.
// Keeps: 256^2 tile, BK=64, XOR k-chunk swizzle (0 conflicts), XCD grouping.

typedef short bf16x8 __attribute__((ext_vector_type(8)));   // 8 bf16 = 4 VGPRs
typedef float f32x4  __attribute__((ext_vector_type(4)));

__device__ __forceinline__ float bf2f(short u) {
    union { unsigned int ui; float f; } cv;
    cv.ui = ((unsigned int)(unsigned short)u) << 16;
    return cv.f;
}
__device__ __forceinline__ short f2bf(float f) {
    __hip_bfloat16 h = __float2bfloat16(f);
    return *reinterpret_cast<short*>(&h);
}

// async global->LDS, 16B per lane. LDS dest = wave-uniform base + lane*16.
__device__ __forceinline__ void gload_lds16(const void* g, void* lds) {
    const unsigned __attribute__((address_space(1)))* gp =
        reinterpret_cast<const unsigned __attribute__((address_space(1)))*>((unsigned long long)g);
    unsigned __attribute__((address_space(3)))* lp =
        reinterpret_cast<unsigned __attribute__((address_space(3)))*>(
            (unsigned int)(unsigned long long)lds);
    __builtin_amdgcn_global_load_lds(gp, lp, 16, 0, 0);
}

// ---------------------------------------------------------------------------
// dtype sniffer (flag: 1 = fp32 inputs, 0 = bf16 inputs).
// ---------------------------------------------------------------------------
__global__ void detect_dtype(const unsigned* __restrict__ x, int* __restrict__ flag) {
    __shared__ int cnt;
    if (threadIdx.x == 0) cnt = 0;
    __syncthreads();
    int c = 0;
    for (int i = threadIdx.x; i < 4096; i += 256) {
        const unsigned u = x[(long)i * 4001 + 3];
        const unsigned b = (u >> 7) & 0xFF;
        c += (b >= 0x70 && b <= 0x87) ? 1 : 0;
    }
    atomicAdd(&cnt, c);
    __syncthreads();
    if (threadIdx.x == 0) *flag = (cnt > 2048) ? 0 : 1;   // HIGH => bf16
}

// convert n elements (n % 8 == 0) at element offset eoff to bf16.
__global__ void convert_any(const void* __restrict__ src, long eoff,
                            short* __restrict__ dst, long n,
                            const int* __restrict__ flag) {
    const int f = *flag;
    const long step = (long)gridDim.x * blockDim.x * 8;
    for (long i = ((long)blockIdx.x * blockDim.x + threadIdx.x) * 8; i < n; i += step) {
        if (f) {
            const float* s = (const float*)src + eoff + i;
            const f32x4 a = *(const f32x4*)s;
            const f32x4 b = *(const f32x4*)(s + 4);
            bf16x8 o;
            o[0] = f2bf(a[0]); o[1] = f2bf(a[1]); o[2] = f2bf(a[2]); o[3] = f2bf(a[3]);
            o[4] = f2bf(b[0]); o[5] = f2bf(b[1]); o[6] = f2bf(b[2]); o[7] = f2bf(b[3]);
            *(bf16x8*)(dst + i) = o;
        } else {
            *(bf16x8*)(dst + i) = *(const bf16x8*)((const short*)src + eoff + i);
        }
    }
}

// ---------------------------------------------------------------------------
// 256x256 tile GEMM core, 512 threads = 8 waves (2M x 4N), wave tile 128x64.
// Half-tile stream: u -> tile T=u>>2, part P=u&3 (P0=A rows0-127, P1=A rows
// 128-255, P2=B rows0-127, P3=B rows128-255), buffer buf[T&1], 2 gloads each.
// Prologue stages u=0..4, vmcnt(2), barrier. Phase (t,p) stages u=5+4t+p.
// ---------------------------------------------------------------------------
__device__ __forceinline__ void gemm256_core(const short* __restrict__ A,
                                             const short* __restrict__ W,
                                             void* __restrict__ C,
                                             const int* flag_fp32,
                                             long m0, int n0, short* lds) {
    constexpr int K = 1024, N = 1024;
    const int tid  = threadIdx.x;
    const int lane = tid & 63;
    const int wid  = tid >> 6;
    const int wm = wid >> 2, wn = wid & 3;

    // staging source: thread covers (row = g*64 + tid>>3, phys kc = tid&7);
    // logical kc = phys ^ (row&7)
    const int srl = tid >> 3;                    // 0..63
    const int kcs = (tid & 7) ^ (srl & 7);
    int aoff[4], boff[4];
    #pragma unroll
    for (int i = 0; i < 4; ++i) {
        const int row = i * 64 + srl;
        aoff[i] = (int)((m0 + row) * K + kcs * 8);
        boff[i] = (n0 + row) * K + kcs * 8;
    }
    const int ldsw = wid * 512;                  // wave's lane0 slot (shorts)

    // stage half-tile u (uniform scalar): 2 gloads
    auto STAGE_HALF = [&](int u) {
        if (u >= 64) return;
        const int T = u >> 2, P = u & 3;
        short* base = lds + (T & 1) * 32768;     // A at +0, B at +16384
        const int kadd = T * 64;
        if (P < 2) {
            const int g = P * 2;
            gload_lds16(A + aoff[g]     + kadd, base + g * 4096 + ldsw);
            gload_lds16(A + aoff[g + 1] + kadd, base + (g + 1) * 4096 + ldsw);
        } else {
            const int g = (P - 2) * 2;
            gload_lds16(W + boff[g]     + kadd, base + 16384 + g * 4096 + ldsw);
            gload_lds16(W + boff[g + 1] + kadd, base + 16384 + (g + 1) * 4096 + ldsw);
        }
    };

    f32x4 acc[8][4] = {};

    const int arow = wm * 128 + (lane & 15);     // + mh*64 + m*16
    const int brow = wn * 64 + (lane & 15);      // + nh*32 + n*16
    const int kx0 = (((lane >> 4)) ^ (lane & 7)) * 8;        // ks=0 chunk
    const int kx1 = ((4 + (lane >> 4)) ^ (lane & 7)) * 8;    // ks=1 chunk

    // prologue: halves 0..4 (tile0 complete + tile1.A.h0), gate, sync
    #pragma unroll
    for (int u = 0; u < 5; ++u) STAGE_HALF(u);
    asm volatile("s_waitcnt vmcnt(2)" ::: "memory");         // u0..3 landed
    __builtin_amdgcn_s_barrier();
    __builtin_amdgcn_sched_barrier(0);

    // one K-tile: 4 quadrant phases
    auto TILE = [&](const short* rA, const short* rB, int t) {
        const int su = 4 * t + 5;
        bf16x8 a[8], b0r[4], b1r[4];
        // ---------- p0: quadrant (mh0, nh0) ----------
        #pragma unroll
        for (int m = 0; m < 4; ++m) {
            a[2 * m]     = *(const bf16x8*)(rA + (arow + m * 16) * 64 + kx0);
            a[2 * m + 1] = *(const bf16x8*)(rA + (arow + m * 16) * 64 + kx1);
        }
        #pragma unroll
        for (int n = 0; n < 2; ++n) {
            b0r[2 * n]     = *(const bf16x8*)(rB + (brow + n * 16) * 64 + kx0);
            b0r[2 * n + 1] = *(const bf16x8*)(rB + (brow + n * 16) * 64 + kx1);
        }
        STAGE_HALF(su);                          // tile t+1 A.h1
        __builtin_amdgcn_sched_barrier(0);
        __builtin_amdgcn_s_barrier();
        asm volatile("s_waitcnt lgkmcnt(0)" ::: "memory");
        __builtin_amdgcn_sched_barrier(0);
        __builtin_amdgcn_s_setprio(1);
        #pragma unroll
        for (int m = 0; m < 4; ++m)
            #pragma unroll
            for (int n = 0; n < 2; ++n) {
                acc[m][n] = __builtin_amdgcn_mfma_f32_16x16x32_bf16(a[2 * m],     b0r[2 * n],     acc[m][n], 0, 0, 0);
                acc[m][n] = __builtin_amdgcn_mfma_f32_16x16x32_bf16(a[2 * m + 1], b0r[2 * n + 1], acc[m][n], 0, 0, 0);
            }
        __builtin_amdgcn_s_setprio(0);
        __builtin_amdgcn_sched_barrier(0);
        __builtin_amdgcn_s_barrier();
        // ---------- p1: quadrant (mh0, nh1) ----------
        #pragma unroll
        for (int n = 0; n < 2; ++n) {
            b1r[2 * n]     = *(const bf16x8*)(rB + (brow + 32 + n * 16) * 64 + kx0);
            b1r[2 * n + 1] = *(const bf16x8*)(rB + (brow + 32 + n * 16) * 64 + kx1);
        }
        STAGE_HALF(su + 1);                      // tile t+1 B.h0
        __builtin_amdgcn_sched_barrier(0);
        __builtin_amdgcn_s_barrier();
        asm volatile("s_waitcnt lgkmcnt(0)" ::: "memory");
        __builtin_amdgcn_sched_barrier(0);
        __builtin_amdgcn_s_setprio(1);
        #pragma unroll
        for (int m = 0; m < 4; ++m)
            #pragma unroll
            for (int n = 0; n < 2; ++n) {
                acc[m][2 + n] = __builtin_amdgcn_mfma_f32_16x16x32_bf16(a[2 * m],     b1r[2 * n],     acc[m][2 + n], 0, 0, 0);
                acc[m][2 + n] = __builtin_amdgcn_mfma_f32_16x16x32_bf16(a[2 * m + 1], b1r[2 * n + 1], acc[m][2 + n], 0, 0, 0);
            }
        __builtin_amdgcn_s_setprio(0);
        __builtin_amdgcn_sched_barrier(0);
        __builtin_amdgcn_s_barrier();
        // ---------- p2: quadrant (mh1, nh0) ----------
        #pragma unroll
        for (int m = 0; m < 4; ++m) {
            a[2 * m]     = *(const bf16x8*)(rA + (arow + 64 + m * 16) * 64 + kx0);
            a[2 * m + 1] = *(const bf16x8*)(rA + (arow + 64 + m * 16) * 64 + kx1);
        }
        STAGE_HALF(su + 2);                      // tile t+1 B.h1
        __builtin_amdgcn_sched_barrier(0);
        __builtin_amdgcn_s_barrier();
        asm volatile("s_waitcnt lgkmcnt(0)" ::: "memory");
        __builtin_amdgcn_sched_barrier(0);
        __builtin_amdgcn_s_setprio(1);
        #pragma unroll
        for (int m = 0; m < 4; ++m)
            #pragma unroll
            for (int n = 0; n < 2; ++n) {
                acc[4 + m][n] = __builtin_amdgcn_mfma_f32_16x16x32_bf16(a[2 * m],     b0r[2 * n],     acc[4 + m][n], 0, 0, 0);
                acc[4 + m][n] = __builtin_amdgcn_mfma_f32_16x16x32_bf16(a[2 * m + 1], b0r[2 * n + 1], acc[4 + m][n], 0, 0, 0);
            }
        __builtin_amdgcn_s_setprio(0);
        __builtin_amdgcn_sched_barrier(0);
        __builtin_amdgcn_s_barrier();
        // ---------- p3: quadrant (mh1, nh1), tile gate ----------
        STAGE_HALF(su + 3);                      // tile t+2 A.h0 (safe: its
                                                 // readers ended >=2 barriers ago)
        if (t < 14)      asm volatile("s_waitcnt vmcnt(2)" ::: "memory");
        else if (t == 14) asm volatile("s_waitcnt vmcnt(0)" ::: "memory");
        __builtin_amdgcn_sched_barrier(0);
        __builtin_amdgcn_s_barrier();
        __builtin_amdgcn_s_setprio(1);
        #pragma unroll
        for (int m = 0; m < 4; ++m)
            #pragma unroll
            for (int n = 0; n < 2; ++n) {
                acc[4 + m][2 + n] = __builtin_amdgcn_mfma_f32_16x16x32_bf16(a[2 * m],     b1r[2 * n],     acc[4 + m][2 + n], 0, 0, 0);
                acc[4 + m][2 + n] = __builtin_amdgcn_mfma_f32_16x16x32_bf16(a[2 * m + 1], b1r[2 * n + 1], acc[4 + m][2 + n], 0, 0, 0);
            }
        __builtin_amdgcn_s_setprio(0);
        __builtin_amdgcn_sched_barrier(0);
        __builtin_amdgcn_s_barrier();
    };

    short* A0 = lds;              // 16384 shorts = 32KB each
    short* B0 = lds + 16384;
    short* A1 = lds + 32768;
    short* B1 = lds + 49152;
    for (int tt = 0; tt < 8; ++tt) {
        TILE(A0, B0, tt * 2);
        TILE(A1, B1, tt * 2 + 1);
    }

    // epilogue: C/D layout col=lane&15, row=(lane>>4)*4+r
    const int f = flag_fp32 ? *flag_fp32 : 0;
    #pragma unroll
    for (int mf = 0; mf < 8; ++mf) {
        #pragma unroll
        for (int nf = 0; nf < 4; ++nf) {
            const int  col   = n0 + wn * 64 + nf * 16 + (lane & 15);
            const long rbase = m0 + wm * 128 + mf * 16 + (lane >> 4) * 4;
            if (f) {
                float* Cf = (float*)C;
                #pragma unroll
                for (int r = 0; r < 4; ++r)
                    Cf[(rbase + r) * N + col] = acc[mf][nf][r];
            } else {
                short* Cs = (short*)C;
                #pragma unroll
                for (int r = 0; r < 4; ++r)
                    Cs[(rbase + r) * N + col] = f2bf(acc[mf][nf][r]);
            }
        }
    }
}

// QKV: 1-D grid, nwg = (Mc/256)*12. XCD-bijective remap with (n-tile, matrix)
// innermost so the 12 blocks sharing an A-panel run on one XCD.
__global__ __launch_bounds__(512, 2) void gemm_qkv256(const short* __restrict__ A,
                                                      const short* __restrict__ W0,
                                                      const short* __restrict__ W1,
                                                      const short* __restrict__ W2,
                                                      short* __restrict__ C0,
                                                      short* __restrict__ C1,
                                                      short* __restrict__ C2) {
    __shared__ __align__(16) short lds[65536];            // 128 KiB
    const int nwg = gridDim.x;
    const int q8  = nwg >> 3;
    const int d   = blockIdx.x;
    const int lin = (d & 7) * q8 + (d >> 3);
    const int x   = lin / 12;
    const int r   = lin - x * 12;
    const int yy  = r / 3;           // 0..3  (n-tile)
    const int z   = r - yy * 3;      // 0..2  (Q/K/V)
    const short* W = (z == 0) ? W0 : (z == 1) ? W1 : W2;
    short*       C = (z == 0) ? C0 : (z == 1) ? C1 : C2;
    gemm256_core(A, W, C, nullptr, (long)x * 256, yy * 256, lds);
}

// Output GEMM: 1-D grid, nwg = (Mc/256)*4. A pre-rebased by caller (A - moff*K).
__global__ __launch_bounds__(512, 2) void gemm_out256(const short* __restrict__ A,
                                                      const short* __restrict__ W,
                                                      void* __restrict__ C,
                                                      long moff,
                                                      const int* __restrict__ flag) {
    __shared__ __align__(16) short lds[65536];
    const int nwg = gridDim.x;
    const int q8  = nwg >> 3;
    const int d   = blockIdx.x;
    const int lin = (d & 7) * q8 + (d >> 3);
    const int x   = lin >> 2;
    const int yy  = lin & 3;
    gemm256_core(A, W, C, flag, moff + (long)x * 256, yy * 256, lds);
}

// ---------------------------------------------------------------------------
// Per-token head mixing: scores = Q[16,64]@K[16,64]^T/8, softmax, Z = P@V.
// One wave per token, 4 tokens per 256-thread block.
// ---------------------------------------------------------------------------
__global__ __launch_bounds__(256) void attn_mix(const short* __restrict__ Q,
                                                const short* __restrict__ K,
                                                const short* __restrict__ V,
                                                short* __restrict__ Z) {
    constexpr int RS = 72;
    __shared__ short sq[4][16 * RS];
    __shared__ short sk[4][16 * RS];
    __shared__ short sv[4][16 * RS];
    __shared__ float sp[4][256];

    const int  tid  = threadIdx.x;
    const int  lane = tid & 63;
    const int  w    = tid >> 6;
    const long tok  = (long)blockIdx.x * 4 + w;

    const short* qg = Q + tok * 1024;
    const short* kg = K + tok * 1024;
    const short* vg = V + tok * 1024;

    #pragma unroll
    for (int it = 0; it < 2; ++it) {
        const int c   = lane + 64 * it;
        const int row = c >> 3;
        const int cc  = (c & 7) * 8;
        *(bf16x8*)&sq[w][row * RS + cc] = *(const bf16x8*)(qg + c * 8);
        *(bf16x8*)&sk[w][row * RS + cc] = *(const bf16x8*)(kg + c * 8);
        *(bf16x8*)&sv[w][row * RS + cc] = *(const bf16x8*)(vg + c * 8);
    }
    __syncthreads();

    const int h  = lane >> 2;
    const int t0 = (lane & 3) * 4;
    float sc[4] = {0.f, 0.f, 0.f, 0.f};
    for (int d = 0; d < 64; ++d) {
        const float qv = bf2f(sq[w][h * RS + d]);
        #pragma unroll
        for (int j = 0; j < 4; ++j)
            sc[j] += qv * bf2f(sk[w][(t0 + j) * RS + d]);
    }
    #pragma unroll
    for (int j = 0; j < 4; ++j) sc[j] *= 0.125f;

    float mx = fmaxf(fmaxf(sc[0], sc[1]), fmaxf(sc[2], sc[3]));
    mx = fmaxf(mx, __shfl_xor(mx, 1));
    mx = fmaxf(mx, __shfl_xor(mx, 2));
    float ex[4], s = 0.f;
    #pragma unroll
    for (int j = 0; j < 4; ++j) { ex[j] = __expf(sc[j] - mx); s += ex[j]; }
    s += __shfl_xor(s, 1);
    s += __shfl_xor(s, 2);
    const float inv = 1.f / s;
    #pragma unroll
    for (int j = 0; j < 4; ++j) sp[w][h * 16 + t0 + j] = ex[j] * inv;
    __syncthreads();

    const int dbase = (lane & 3) * 16;
    float o[16] = {};
    for (int t = 0; t < 16; ++t) {
        const float p = sp[w][h * 16 + t];
        const bf16x8 v0 = *(const bf16x8*)&sv[w][t * RS + dbase];
        const bf16x8 v1 = *(const bf16x8*)&sv[w][t * RS + dbase + 8];
        #pragma unroll
        for (int e = 0; e < 8; ++e) {
            o[e]     += p * bf2f(v0[e]);
            o[e + 8] += p * bf2f(v1[e]);
        }
    }
    bf16x8 ov0, ov1;
    #pragma unroll
    for (int e = 0; e < 8; ++e) { ov0[e] = f2bf(o[e]); ov1[e] = f2bf(o[e + 8]); }
    *(bf16x8*)(Z + tok * 1024 + lane * 16)     = ov0;
    *(bf16x8*)(Z + tok * 1024 + lane * 16 + 8) = ov1;
}

// ---------------------------------------------------------------------------
extern "C" void kernel_launch(void* const* d_in, const int* in_sizes, int n_in,
                              void* d_out, int out_size, void* d_ws, size_t ws_size,
                              hipStream_t stream) {
    const void* X = d_in[0];                   // [32768,1024] fp32 (detected)

    const long TOT = 32768;
    constexpr long WELEM = 1024 * 1024;

    char* ws   = (char*)d_ws;
    int*  flag = (int*)ws;
    short* Wqb = (short*)(ws + 256);
    short* Wkb = Wqb + WELEM;
    short* Wvb = Wkb + WELEM;
    short* Wob = Wvb + WELEM;
    short* dyn = Wob + WELEM;

    const size_t fixed = 256 + 4 * WELEM * 2;
    long chunk = 256;
    const long tiers[4] = {32768, 8192, 2048, 512};
    for (int i = 0; i < 4; ++i)
        if (fixed + (size_t)6 * tiers[i] * 1024 * 2 <= ws_size) { chunk = tiers[i]; break; }

    short* Xb = dyn;                 // chunk*1024 bf16
    short* Qb = Xb + chunk * 1024;
    short* Kb = Qb + chunk * 1024;
    short* Vb = Kb + chunk * 1024;
    short* Zb = Vb + chunk * 1024;

    detect_dtype<<<1, 256, 0, stream>>>((const unsigned*)X, flag);
    convert_any<<<512, 256, 0, stream>>>(d_in[1], 0, Wqb, WELEM, flag);
    convert_any<<<512, 256, 0, stream>>>(d_in[2], 0, Wkb, WELEM, flag);
    convert_any<<<512, 256, 0, stream>>>(d_in[3], 0, Wvb, WELEM, flag);
    convert_any<<<512, 256, 0, stream>>>(d_in[4], 0, Wob, WELEM, flag);

    for (long t0 = 0; t0 < TOT; t0 += chunk) {
        convert_any<<<2048, 256, 0, stream>>>(X, t0 * 1024, Xb, chunk * 1024, flag);
        gemm_qkv256<<<dim3((chunk / 256) * 12), 512, 0, stream>>>(Xb, Wqb, Wkb, Wvb,
                                                                  Qb, Kb, Vb);
        attn_mix<<<dim3(chunk / 4), 256, 0, stream>>>(Qb, Kb, Vb, Zb);
        gemm_out256<<<dim3((chunk / 256) * 4), 512, 0, stream>>>(Zb - t0 * 1024, Wob,
                                                                 d_out, t0, flag);
    }
}

// Round 12
// 406.776 us; speedup vs baseline: 1.1345x; 1.1345x over previous
//
#include <hip/hip_runtime.h>
#include <hip/hip_bf16.h>

// LlamaAttention_49392123904401 — per-token head-mixing "attention".
// fp32 inputs (runtime-detected), bf16 MFMA compute, output in input dtype.
// Round 12: consolidation. GEMM core reverted to the round-6 version (best
// measured: qkv 216us, MfmaUtil 42%, 0 bank conflicts). All dtype conversions
// merged into ONE grid-strided dispatch over contiguous [Wq|Wk|Wv|Wo|X] ws.
// Launches: detect, convert_all, gemm_qkv256, attn_mix, gemm_out256 (5 total).

typedef short bf16x8 __attribute__((ext_vector_type(8)));   // 8 bf16 = 4 VGPRs
typedef float f32x4  __attribute__((ext_vector_type(4)));

__device__ __forceinline__ float bf2f(short u) {
    union { unsigned int ui; float f; } cv;
    cv.ui = ((unsigned int)(unsigned short)u) << 16;
    return cv.f;
}
__device__ __forceinline__ short f2bf(float f) {
    __hip_bfloat16 h = __float2bfloat16(f);
    return *reinterpret_cast<short*>(&h);
}

// async global->LDS, 16B per lane. LDS dest = wave-uniform base + lane*16.
__device__ __forceinline__ void gload_lds16(const void* g, void* lds) {
    const unsigned __attribute__((address_space(1)))* gp =
        reinterpret_cast<const unsigned __attribute__((address_space(1)))*>((unsigned long long)g);
    unsigned __attribute__((address_space(3)))* lp =
        reinterpret_cast<unsigned __attribute__((address_space(3)))*>(
            (unsigned int)(unsigned long long)lds);
    __builtin_amdgcn_global_load_lds(gp, lp, 16, 0, 0);
}

// ---------------------------------------------------------------------------
// dtype sniffer (flag: 1 = fp32 inputs, 0 = bf16 inputs).
// ---------------------------------------------------------------------------
__global__ void detect_dtype(const unsigned* __restrict__ x, int* __restrict__ flag) {
    __shared__ int cnt;
    if (threadIdx.x == 0) cnt = 0;
    __syncthreads();
    int c = 0;
    for (int i = threadIdx.x; i < 4096; i += 256) {
        const unsigned u = x[(long)i * 4001 + 3];
        const unsigned b = (u >> 7) & 0xFF;
        c += (b >= 0x70 && b <= 0x87) ? 1 : 0;
    }
    atomicAdd(&cnt, c);
    __syncthreads();
    if (threadIdx.x == 0) *flag = (cnt > 2048) ? 0 : 1;   // HIGH => bf16
}

// ---------------------------------------------------------------------------
// ONE conversion pass: dst is the contiguous bf16 region [Wq|Wk|Wv|Wo|X]
// (4*WELEM + XN elems). Sources: i<4*WELEM -> weight (d_in[1+ (i>>20)]),
// else X. Each thread handles 8 elems; segment boundaries are 1M-aligned so
// an 8-chunk never straddles segments.
// ---------------------------------------------------------------------------
__global__ void convert_all(const void* __restrict__ X,
                            const void* __restrict__ W0, const void* __restrict__ W1,
                            const void* __restrict__ W2, const void* __restrict__ W3,
                            short* __restrict__ dst, long total,
                            const int* __restrict__ flag) {
    constexpr long WELEM = 1024 * 1024;
    const int f = *flag;
    const long step = (long)gridDim.x * blockDim.x * 8;
    for (long i = ((long)blockIdx.x * blockDim.x + threadIdx.x) * 8; i < total; i += step) {
        const void* src;
        long off;
        if (i < 4 * WELEM) {
            const int w = (int)(i >> 20);
            src = (w == 0) ? W0 : (w == 1) ? W1 : (w == 2) ? W2 : W3;
            off = i & (WELEM - 1);
        } else {
            src = X;
            off = i - 4 * WELEM;
        }
        if (f) {
            const float* s = (const float*)src + off;
            const f32x4 a = *(const f32x4*)s;
            const f32x4 b = *(const f32x4*)(s + 4);
            bf16x8 o;
            o[0] = f2bf(a[0]); o[1] = f2bf(a[1]); o[2] = f2bf(a[2]); o[3] = f2bf(a[3]);
            o[4] = f2bf(b[0]); o[5] = f2bf(b[1]); o[6] = f2bf(b[2]); o[7] = f2bf(b[3]);
            *(bf16x8*)(dst + i) = o;
        } else {
            *(bf16x8*)(dst + i) = *(const bf16x8*)((const short*)src + off);
        }
    }
}

// ---------------------------------------------------------------------------
// 256x256 tile GEMM core (round-6 version — best measured).
// 512 threads = 8 waves (2Mx4N), per-wave 128x64 output (8x4 frags).
// BK=64, 16 K-tiles, double-buffered, 2 phases/tile (ks-halves).
// Per phase: 12 ds_read_b128 (pre-barrier) + 32 MFMA; stage A(t+1)@ph0,
// B(t+1)@ph1; vmcnt(0)+barrier once per tile.
// LDS k-chunk XOR swizzle: phys_kc = kc ^ (row&7); staging pre-applies the
// inverse swizzle on the GLOBAL source address (rule #21 both-sides).
// ---------------------------------------------------------------------------
__device__ __forceinline__ void gemm256_core(const short* __restrict__ A,
                                             const short* __restrict__ W,
                                             void* __restrict__ C,
                                             const int* flag_fp32,
                                             long m0, int n0, short* lds) {
    constexpr int K = 1024, N = 1024;
    const int tid  = threadIdx.x;
    const int lane = tid & 63;
    const int wid  = tid >> 6;
    const int wm = wid >> 2, wn = wid & 3;

    short* A0 = lds;              // 16384 shorts = 32KB each
    short* B0 = lds + 16384;
    short* A1 = lds + 32768;
    short* B1 = lds + 49152;

    const int srl = tid >> 3;                    // 0..63
    const int kcs = (tid & 7) ^ (srl & 7);       // logical k-chunk for this lane
    int aoff[4], boff[4];
    #pragma unroll
    for (int i = 0; i < 4; ++i) {
        const int row = i * 64 + srl;
        aoff[i] = (int)((m0 + row) * K + kcs * 8);
        boff[i] = (n0 + row) * K + kcs * 8;
    }
    const int ldsw = wid * 512;                  // wave's lane0 slot (shorts)

    f32x4 acc[8][4] = {};

    // prologue: tile 0 fully staged, drained, synced
    #pragma unroll
    for (int i = 0; i < 4; ++i) gload_lds16(A + aoff[i], A0 + i * 4096 + ldsw);
    #pragma unroll
    for (int i = 0; i < 4; ++i) gload_lds16(W + boff[i], B0 + i * 4096 + ldsw);
    asm volatile("s_waitcnt vmcnt(0)" ::: "memory");
    __builtin_amdgcn_s_barrier();

    for (int t = 0; t < 16; ++t) {
        const int cur = t & 1;
        const short* rA = cur ? A1 : A0;         // read buffers (tile t)
        const short* rB = cur ? B1 : B0;
        short* sA = cur ? A0 : A1;               // stage buffers (tile t+1)
        short* sB = cur ? B0 : B1;
        const int kadd = (t + 1) * 64;
        const bool more = (t < 15);

        #pragma unroll
        for (int ks = 0; ks < 2; ++ks) {
            const int kx8 = ((ks * 4 + (lane >> 4)) ^ (lane & 7)) * 8;
            bf16x8 af[8], bfr[4];
            #pragma unroll
            for (int m = 0; m < 8; ++m)
                af[m] = *(const bf16x8*)(rA + ((wm * 128 + m * 16 + (lane & 15)) * 64) + kx8);
            #pragma unroll
            for (int n = 0; n < 4; ++n)
                bfr[n] = *(const bf16x8*)(rB + ((wn * 64 + n * 16 + (lane & 15)) * 64) + kx8);
            __builtin_amdgcn_sched_barrier(0);
            __builtin_amdgcn_s_barrier();              // bar_a
            __builtin_amdgcn_sched_barrier(0);
            if (more) {
                if (ks == 0) {
                    #pragma unroll
                    for (int i = 0; i < 4; ++i)
                        gload_lds16(A + aoff[i] + kadd, sA + i * 4096 + ldsw);
                } else {
                    #pragma unroll
                    for (int i = 0; i < 4; ++i)
                        gload_lds16(W + boff[i] + kadd, sB + i * 4096 + ldsw);
                }
            }
            asm volatile("s_waitcnt lgkmcnt(0)" ::: "memory");
            __builtin_amdgcn_sched_barrier(0);
            __builtin_amdgcn_s_setprio(1);
            #pragma unroll
            for (int m = 0; m < 8; ++m)
                #pragma unroll
                for (int n = 0; n < 4; ++n)
                    acc[m][n] = __builtin_amdgcn_mfma_f32_16x16x32_bf16(
                                    af[m], bfr[n], acc[m][n], 0, 0, 0);
            __builtin_amdgcn_s_setprio(0);
            __builtin_amdgcn_sched_barrier(0);
            if (ks == 1) {
                asm volatile("s_waitcnt vmcnt(0)" ::: "memory");
                __builtin_amdgcn_s_barrier();          // bar_b
            }
        }
    }

    // epilogue: C/D layout col=lane&15, row=(lane>>4)*4+r
    const int f = flag_fp32 ? *flag_fp32 : 0;
    #pragma unroll
    for (int mf = 0; mf < 8; ++mf) {
        #pragma unroll
        for (int nf = 0; nf < 4; ++nf) {
            const int  col   = n0 + wn * 64 + nf * 16 + (lane & 15);
            const long rbase = m0 + wm * 128 + mf * 16 + (lane >> 4) * 4;
            if (f) {
                float* Cf = (float*)C;
                #pragma unroll
                for (int r = 0; r < 4; ++r)
                    Cf[(rbase + r) * N + col] = acc[mf][nf][r];
            } else {
                short* Cs = (short*)C;
                #pragma unroll
                for (int r = 0; r < 4; ++r)
                    Cs[(rbase + r) * N + col] = f2bf(acc[mf][nf][r]);
            }
        }
    }
}

// QKV: 1-D grid, nwg = (Mc/256)*12. XCD-bijective remap with (n-tile, matrix)
// innermost so the 12 blocks sharing an A-panel run on one XCD.
__global__ __launch_bounds__(512, 2) void gemm_qkv256(const short* __restrict__ A,
                                                      const short* __restrict__ W0,
                                                      const short* __restrict__ W1,
                                                      const short* __restrict__ W2,
                                                      short* __restrict__ C0,
                                                      short* __restrict__ C1,
                                                      short* __restrict__ C2) {
    __shared__ __align__(16) short lds[65536];            // 128 KiB
    const int nwg = gridDim.x;
    const int q8  = nwg >> 3;
    const int d   = blockIdx.x;
    const int lin = (d & 7) * q8 + (d >> 3);
    const int x   = lin / 12;
    const int r   = lin - x * 12;
    const int yy  = r / 3;           // 0..3  (n-tile)
    const int z   = r - yy * 3;      // 0..2  (Q/K/V)
    const short* W = (z == 0) ? W0 : (z == 1) ? W1 : W2;
    short*       C = (z == 0) ? C0 : (z == 1) ? C1 : C2;
    gemm256_core(A, W, C, nullptr, (long)x * 256, yy * 256, lds);
}

// Output GEMM: 1-D grid, nwg = (Mc/256)*4. A pre-rebased by caller (A - moff*K).
__global__ __launch_bounds__(512, 2) void gemm_out256(const short* __restrict__ A,
                                                      const short* __restrict__ W,
                                                      void* __restrict__ C,
                                                      long moff,
                                                      const int* __restrict__ flag) {
    __shared__ __align__(16) short lds[65536];
    const int nwg = gridDim.x;
    const int q8  = nwg >> 3;
    const int d   = blockIdx.x;
    const int lin = (d & 7) * q8 + (d >> 3);
    const int x   = lin >> 2;
    const int yy  = lin & 3;
    gemm256_core(A, W, C, flag, moff + (long)x * 256, yy * 256, lds);
}

// ---------------------------------------------------------------------------
// Per-token head mixing: scores = Q[16,64]@K[16,64]^T/8, softmax, Z = P@V.
// One wave per token, 4 tokens per 256-thread block.
// ---------------------------------------------------------------------------
__global__ __launch_bounds__(256) void attn_mix(const short* __restrict__ Q,
                                                const short* __restrict__ K,
                                                const short* __restrict__ V,
                                                short* __restrict__ Z) {
    constexpr int RS = 72;
    __shared__ short sq[4][16 * RS];
    __shared__ short sk[4][16 * RS];
    __shared__ short sv[4][16 * RS];
    __shared__ float sp[4][256];

    const int  tid  = threadIdx.x;
    const int  lane = tid & 63;
    const int  w    = tid >> 6;
    const long tok  = (long)blockIdx.x * 4 + w;

    const short* qg = Q + tok * 1024;
    const short* kg = K + tok * 1024;
    const short* vg = V + tok * 1024;

    #pragma unroll
    for (int it = 0; it < 2; ++it) {
        const int c   = lane + 64 * it;
        const int row = c >> 3;
        const int cc  = (c & 7) * 8;
        *(bf16x8*)&sq[w][row * RS + cc] = *(const bf16x8*)(qg + c * 8);
        *(bf16x8*)&sk[w][row * RS + cc] = *(const bf16x8*)(kg + c * 8);
        *(bf16x8*)&sv[w][row * RS + cc] = *(const bf16x8*)(vg + c * 8);
    }
    __syncthreads();

    const int h  = lane >> 2;
    const int t0 = (lane & 3) * 4;
    float sc[4] = {0.f, 0.f, 0.f, 0.f};
    for (int d = 0; d < 64; ++d) {
        const float qv = bf2f(sq[w][h * RS + d]);
        #pragma unroll
        for (int j = 0; j < 4; ++j)
            sc[j] += qv * bf2f(sk[w][(t0 + j) * RS + d]);
    }
    #pragma unroll
    for (int j = 0; j < 4; ++j) sc[j] *= 0.125f;

    float mx = fmaxf(fmaxf(sc[0], sc[1]), fmaxf(sc[2], sc[3]));
    mx = fmaxf(mx, __shfl_xor(mx, 1));
    mx = fmaxf(mx, __shfl_xor(mx, 2));
    float ex[4], s = 0.f;
    #pragma unroll
    for (int j = 0; j < 4; ++j) { ex[j] = __expf(sc[j] - mx); s += ex[j]; }
    s += __shfl_xor(s, 1);
    s += __shfl_xor(s, 2);
    const float inv = 1.f / s;
    #pragma unroll
    for (int j = 0; j < 4; ++j) sp[w][h * 16 + t0 + j] = ex[j] * inv;
    __syncthreads();

    const int dbase = (lane & 3) * 16;
    float o[16] = {};
    for (int t = 0; t < 16; ++t) {
        const float p = sp[w][h * 16 + t];
        const bf16x8 v0 = *(const bf16x8*)&sv[w][t * RS + dbase];
        const bf16x8 v1 = *(const bf16x8*)&sv[w][t * RS + dbase + 8];
        #pragma unroll
        for (int e = 0; e < 8; ++e) {
            o[e]     += p * bf2f(v0[e]);
            o[e + 8] += p * bf2f(v1[e]);
        }
    }
    bf16x8 ov0, ov1;
    #pragma unroll
    for (int e = 0; e < 8; ++e) { ov0[e] = f2bf(o[e]); ov1[e] = f2bf(o[e + 8]); }
    *(bf16x8*)(Z + tok * 1024 + lane * 16)     = ov0;
    *(bf16x8*)(Z + tok * 1024 + lane * 16 + 8) = ov1;
}

// ---------------------------------------------------------------------------
extern "C" void kernel_launch(void* const* d_in, const int* in_sizes, int n_in,
                              void* d_out, int out_size, void* d_ws, size_t ws_size,
                              hipStream_t stream) {
    const void* X = d_in[0];                   // [32768,1024] fp32 (detected)

    const long TOT = 32768;
    constexpr long WELEM = 1024 * 1024;

    char* ws   = (char*)d_ws;
    int*  flag = (int*)ws;
    short* Wqb = (short*)(ws + 256);           // [Wq|Wk|Wv|Wo|Xb] contiguous
    short* Wkb = Wqb + WELEM;
    short* Wvb = Wkb + WELEM;
    short* Wob = Wvb + WELEM;
    short* dyn = Wob + WELEM;

    const size_t fixed = 256 + 4 * WELEM * 2;
    long chunk = 256;
    const long tiers[4] = {32768, 8192, 2048, 512};
    for (int i = 0; i < 4; ++i)
        if (fixed + (size_t)6 * tiers[i] * 1024 * 2 <= ws_size) { chunk = tiers[i]; break; }

    short* Xb = dyn;                 // chunk*1024 bf16 (contiguous after Wob)
    short* Qb = Xb + chunk * 1024;
    short* Kb = Qb + chunk * 1024;
    short* Vb = Kb + chunk * 1024;
    short* Zb = Vb + chunk * 1024;

    detect_dtype<<<1, 256, 0, stream>>>((const unsigned*)X, flag);

    if (chunk == TOT) {
        // single merged conversion: weights + full X in one dispatch
        convert_all<<<2048, 256, 0, stream>>>(X, d_in[1], d_in[2], d_in[3], d_in[4],
                                              Wqb, 4 * WELEM + TOT * 1024, flag);
        gemm_qkv256<<<dim3((TOT / 256) * 12), 512, 0, stream>>>(Xb, Wqb, Wkb, Wvb,
                                                                Qb, Kb, Vb);
        attn_mix<<<dim3(TOT / 4), 256, 0, stream>>>(Qb, Kb, Vb, Zb);
        gemm_out256<<<dim3((TOT / 256) * 4), 512, 0, stream>>>(Zb, Wob, d_out, 0, flag);
    } else {
        // chunked fallback: weights once, X per chunk
        convert_all<<<512, 256, 0, stream>>>(X, d_in[1], d_in[2], d_in[3], d_in[4],
                                             Wqb, 4 * WELEM, flag);
        for (long t0 = 0; t0 < TOT; t0 += chunk) {
            // reuse convert_all for the X chunk only (offset via pointer math)
            convert_all<<<2048, 256, 0, stream>>>(
                (const void*)((const char*)X + (size_t)t0 * 1024 * 4),
                d_in[1], d_in[2], d_in[3], d_in[4],
                Xb - 4 * WELEM,                 // dst base so i>=4M maps to Xb
                4 * WELEM + chunk * 1024, flag);
            // NOTE: the weight region [0,4M) would be rewritten identically —
            // wasteful but correct; chunked path is a capacity fallback only.
            gemm_qkv256<<<dim3((chunk / 256) * 12), 512, 0, stream>>>(Xb, Wqb, Wkb, Wvb,
                                                                      Qb, Kb, Vb);
            attn_mix<<<dim3(chunk / 4), 256, 0, stream>>>(Qb, Kb, Vb, Zb);
            gemm_out256<<<dim3((chunk / 256) * 4), 512, 0, stream>>>(Zb - t0 * 1024, Wob,
                                                                     d_out, t0, flag);
        }
    }
}

// Round 13
// 404.507 us; speedup vs baseline: 1.1408x; 1.0056x over previous
//
#include <hip/hip_runtime.h>
#include <hip/hip_bf16.h>

// LlamaAttention_49392123904401 — per-token head-mixing "attention".
// fp32 inputs (runtime-detected), bf16 MFMA compute, output in input dtype.
// Round 13: cut LDS-read traffic 33% via fatter wave tiles. 4 waves/block
// (256 thr), wave tile 128x128 (acc 8x8 f32x4 = 256 regs/lane, 1 wave/SIMD).
// Per-CU per-K-tile LDS reads drop 192KB->128KB (2260->1505 cyc) at the same
// MFMA floor (2484 cyc). Schedule/swizzle/staging = round-6 skeleton (best
// measured), remapped for 256 staging threads.

typedef short bf16x8 __attribute__((ext_vector_type(8)));   // 8 bf16 = 4 VGPRs
typedef float f32x4  __attribute__((ext_vector_type(4)));

__device__ __forceinline__ float bf2f(short u) {
    union { unsigned int ui; float f; } cv;
    cv.ui = ((unsigned int)(unsigned short)u) << 16;
    return cv.f;
}
__device__ __forceinline__ short f2bf(float f) {
    __hip_bfloat16 h = __float2bfloat16(f);
    return *reinterpret_cast<short*>(&h);
}

// async global->LDS, 16B per lane. LDS dest = wave-uniform base + lane*16.
__device__ __forceinline__ void gload_lds16(const void* g, void* lds) {
    const unsigned __attribute__((address_space(1)))* gp =
        reinterpret_cast<const unsigned __attribute__((address_space(1)))*>((unsigned long long)g);
    unsigned __attribute__((address_space(3)))* lp =
        reinterpret_cast<unsigned __attribute__((address_space(3)))*>(
            (unsigned int)(unsigned long long)lds);
    __builtin_amdgcn_global_load_lds(gp, lp, 16, 0, 0);
}

// ---------------------------------------------------------------------------
// dtype sniffer (flag: 1 = fp32 inputs, 0 = bf16 inputs).
// ---------------------------------------------------------------------------
__global__ void detect_dtype(const unsigned* __restrict__ x, int* __restrict__ flag) {
    __shared__ int cnt;
    if (threadIdx.x == 0) cnt = 0;
    __syncthreads();
    int c = 0;
    for (int i = threadIdx.x; i < 4096; i += 256) {
        const unsigned u = x[(long)i * 4001 + 3];
        const unsigned b = (u >> 7) & 0xFF;
        c += (b >= 0x70 && b <= 0x87) ? 1 : 0;
    }
    atomicAdd(&cnt, c);
    __syncthreads();
    if (threadIdx.x == 0) *flag = (cnt > 2048) ? 0 : 1;   // HIGH => bf16
}

// ---------------------------------------------------------------------------
// ONE conversion pass over contiguous [Wq|Wk|Wv|Wo|X] bf16 region.
// ---------------------------------------------------------------------------
__global__ void convert_all(const void* __restrict__ X,
                            const void* __restrict__ W0, const void* __restrict__ W1,
                            const void* __restrict__ W2, const void* __restrict__ W3,
                            short* __restrict__ dst, long total,
                            const int* __restrict__ flag) {
    constexpr long WELEM = 1024 * 1024;
    const int f = *flag;
    const long step = (long)gridDim.x * blockDim.x * 8;
    for (long i = ((long)blockIdx.x * blockDim.x + threadIdx.x) * 8; i < total; i += step) {
        const void* src;
        long off;
        if (i < 4 * WELEM) {
            const int w = (int)(i >> 20);
            src = (w == 0) ? W0 : (w == 1) ? W1 : (w == 2) ? W2 : W3;
            off = i & (WELEM - 1);
        } else {
            src = X;
            off = i - 4 * WELEM;
        }
        if (f) {
            const float* s = (const float*)src + off;
            const f32x4 a = *(const f32x4*)s;
            const f32x4 b = *(const f32x4*)(s + 4);
            bf16x8 o;
            o[0] = f2bf(a[0]); o[1] = f2bf(a[1]); o[2] = f2bf(a[2]); o[3] = f2bf(a[3]);
            o[4] = f2bf(b[0]); o[5] = f2bf(b[1]); o[6] = f2bf(b[2]); o[7] = f2bf(b[3]);
            *(bf16x8*)(dst + i) = o;
        } else {
            *(bf16x8*)(dst + i) = *(const bf16x8*)((const short*)src + off);
        }
    }
}

// ---------------------------------------------------------------------------
// 256x256 tile GEMM core — 256 threads = 4 waves (2M x 2N), wave tile 128x128.
// acc: 8x8 f32x4 per lane (256 regs). BK=64, 16 K-tiles, double-buffered,
// 2 phases/tile (ks-halves). Per phase: 16 ds_read_b128 (pre-barrier) +
// 64 MFMA; stage A(t+1)@ph0 (8 gloads), B(t+1)@ph1; vmcnt(0)+barrier per tile.
// LDS k-chunk XOR swizzle: phys_kc = kc ^ (row&7); staging pre-applies the
// inverse swizzle on the GLOBAL source address (rule #21 both-sides).
// ---------------------------------------------------------------------------
__device__ __forceinline__ void gemm256_core(const short* __restrict__ A,
                                             const short* __restrict__ W,
                                             void* __restrict__ C,
                                             const int* flag_fp32,
                                             long m0, int n0, short* lds) {
    constexpr int K = 1024, N = 1024;
    const int tid  = threadIdx.x;
    const int lane = tid & 63;
    const int wid  = tid >> 6;                   // 0..3
    const int wm = wid >> 1, wn = wid & 1;

    short* A0 = lds;              // 16384 shorts = 32KB each
    short* B0 = lds + 16384;
    short* A1 = lds + 32768;
    short* B1 = lds + 49152;

    // staging: 256 threads cover 32 rows x 8 chunks per gload group.
    // thread -> (row = g*32 + tid>>3, phys chunk = tid&7); logical chunk =
    // phys ^ (row&7); row&7 == (tid>>3)&7 since g*32 % 8 == 0.
    const int srl = tid >> 3;                    // 0..31
    const int kcs = (tid & 7) ^ (srl & 7);
    int aoff[8], boff[8];
    #pragma unroll
    for (int i = 0; i < 8; ++i) {
        const int row = i * 32 + srl;
        aoff[i] = (int)((m0 + row) * K + kcs * 8);
        boff[i] = (n0 + row) * K + kcs * 8;
    }
    const int ldsw = wid * 512;                  // wave's lane0 slot (shorts)

    f32x4 acc[8][8] = {};

    // prologue: tile 0 fully staged, drained, synced
    #pragma unroll
    for (int i = 0; i < 8; ++i) gload_lds16(A + aoff[i], A0 + i * 2048 + ldsw);
    #pragma unroll
    for (int i = 0; i < 8; ++i) gload_lds16(W + boff[i], B0 + i * 2048 + ldsw);
    asm volatile("s_waitcnt vmcnt(0)" ::: "memory");
    __builtin_amdgcn_s_barrier();

    const int arow = wm * 128 + (lane & 15);     // + m*16
    const int brow = wn * 128 + (lane & 15);     // + n*16

    for (int t = 0; t < 16; ++t) {
        const int cur = t & 1;
        const short* rA = cur ? A1 : A0;         // read buffers (tile t)
        const short* rB = cur ? B1 : B0;
        short* sA = cur ? A0 : A1;               // stage buffers (tile t+1)
        short* sB = cur ? B0 : B1;
        const int kadd = (t + 1) * 64;
        const bool more = (t < 15);

        #pragma unroll
        for (int ks = 0; ks < 2; ++ks) {
            const int kx8 = ((ks * 4 + (lane >> 4)) ^ (lane & 7)) * 8;
            bf16x8 af[8], bfr[8];
            #pragma unroll
            for (int m = 0; m < 8; ++m)
                af[m] = *(const bf16x8*)(rA + ((arow + m * 16) * 64) + kx8);
            #pragma unroll
            for (int n = 0; n < 8; ++n)
                bfr[n] = *(const bf16x8*)(rB + ((brow + n * 16) * 64) + kx8);
            __builtin_amdgcn_sched_barrier(0);
            __builtin_amdgcn_s_barrier();              // bar_a
            __builtin_amdgcn_sched_barrier(0);
            if (more) {
                if (ks == 0) {
                    #pragma unroll
                    for (int i = 0; i < 8; ++i)
                        gload_lds16(A + aoff[i] + kadd, sA + i * 2048 + ldsw);
                } else {
                    #pragma unroll
                    for (int i = 0; i < 8; ++i)
                        gload_lds16(W + boff[i] + kadd, sB + i * 2048 + ldsw);
                }
            }
            asm volatile("s_waitcnt lgkmcnt(0)" ::: "memory");
            __builtin_amdgcn_sched_barrier(0);         // rule 18: no MFMA hoist
            __builtin_amdgcn_s_setprio(1);
            #pragma unroll
            for (int m = 0; m < 8; ++m)
                #pragma unroll
                for (int n = 0; n < 8; ++n)
                    acc[m][n] = __builtin_amdgcn_mfma_f32_16x16x32_bf16(
                                    af[m], bfr[n], acc[m][n], 0, 0, 0);
            __builtin_amdgcn_s_setprio(0);
            __builtin_amdgcn_sched_barrier(0);
            if (ks == 1) {
                asm volatile("s_waitcnt vmcnt(0)" ::: "memory");
                __builtin_amdgcn_s_barrier();          // bar_b
            }
        }
    }

    // epilogue: C/D layout col=lane&15, row=(lane>>4)*4+r
    const int f = flag_fp32 ? *flag_fp32 : 0;
    #pragma unroll
    for (int mf = 0; mf < 8; ++mf) {
        #pragma unroll
        for (int nf = 0; nf < 8; ++nf) {
            const int  col   = n0 + wn * 128 + nf * 16 + (lane & 15);
            const long rbase = m0 + wm * 128 + mf * 16 + (lane >> 4) * 4;
            if (f) {
                float* Cf = (float*)C;
                #pragma unroll
                for (int r = 0; r < 4; ++r)
                    Cf[(rbase + r) * N + col] = acc[mf][nf][r];
            } else {
                short* Cs = (short*)C;
                #pragma unroll
                for (int r = 0; r < 4; ++r)
                    Cs[(rbase + r) * N + col] = f2bf(acc[mf][nf][r]);
            }
        }
    }
}

// QKV: 1-D grid, nwg = (Mc/256)*12. XCD-bijective remap with (n-tile, matrix)
// innermost so the 12 blocks sharing an A-panel run on one XCD.
__global__ __launch_bounds__(256, 1) void gemm_qkv256(const short* __restrict__ A,
                                                      const short* __restrict__ W0,
                                                      const short* __restrict__ W1,
                                                      const short* __restrict__ W2,
                                                      short* __restrict__ C0,
                                                      short* __restrict__ C1,
                                                      short* __restrict__ C2) {
    __shared__ __align__(16) short lds[65536];            // 128 KiB
    const int nwg = gridDim.x;
    const int q8  = nwg >> 3;
    const int d   = blockIdx.x;
    const int lin = (d & 7) * q8 + (d >> 3);
    const int x   = lin / 12;
    const int r   = lin - x * 12;
    const int yy  = r / 3;           // 0..3  (n-tile)
    const int z   = r - yy * 3;      // 0..2  (Q/K/V)
    const short* W = (z == 0) ? W0 : (z == 1) ? W1 : W2;
    short*       C = (z == 0) ? C0 : (z == 1) ? C1 : C2;
    gemm256_core(A, W, C, nullptr, (long)x * 256, yy * 256, lds);
}

// Output GEMM: 1-D grid, nwg = (Mc/256)*4. A pre-rebased by caller (A - moff*K).
__global__ __launch_bounds__(256, 1) void gemm_out256(const short* __restrict__ A,
                                                      const short* __restrict__ W,
                                                      void* __restrict__ C,
                                                      long moff,
                                                      const int* __restrict__ flag) {
    __shared__ __align__(16) short lds[65536];
    const int nwg = gridDim.x;
    const int q8  = nwg >> 3;
    const int d   = blockIdx.x;
    const int lin = (d & 7) * q8 + (d >> 3);
    const int x   = lin >> 2;
    const int yy  = lin & 3;
    gemm256_core(A, W, C, flag, moff + (long)x * 256, yy * 256, lds);
}

// ---------------------------------------------------------------------------
// Per-token head mixing: scores = Q[16,64]@K[16,64]^T/8, softmax, Z = P@V.
// One wave per token, 4 tokens per 256-thread block.
// ---------------------------------------------------------------------------
__global__ __launch_bounds__(256) void attn_mix(const short* __restrict__ Q,
                                                const short* __restrict__ K,
                                                const short* __restrict__ V,
                                                short* __restrict__ Z) {
    constexpr int RS = 72;
    __shared__ short sq[4][16 * RS];
    __shared__ short sk[4][16 * RS];
    __shared__ short sv[4][16 * RS];
    __shared__ float sp[4][256];

    const int  tid  = threadIdx.x;
    const int  lane = tid & 63;
    const int  w    = tid >> 6;
    const long tok  = (long)blockIdx.x * 4 + w;

    const short* qg = Q + tok * 1024;
    const short* kg = K + tok * 1024;
    const short* vg = V + tok * 1024;

    #pragma unroll
    for (int it = 0; it < 2; ++it) {
        const int c   = lane + 64 * it;
        const int row = c >> 3;
        const int cc  = (c & 7) * 8;
        *(bf16x8*)&sq[w][row * RS + cc] = *(const bf16x8*)(qg + c * 8);
        *(bf16x8*)&sk[w][row * RS + cc] = *(const bf16x8*)(kg + c * 8);
        *(bf16x8*)&sv[w][row * RS + cc] = *(const bf16x8*)(vg + c * 8);
    }
    __syncthreads();

    const int h  = lane >> 2;
    const int t0 = (lane & 3) * 4;
    float sc[4] = {0.f, 0.f, 0.f, 0.f};
    for (int d = 0; d < 64; ++d) {
        const float qv = bf2f(sq[w][h * RS + d]);
        #pragma unroll
        for (int j = 0; j < 4; ++j)
            sc[j] += qv * bf2f(sk[w][(t0 + j) * RS + d]);
    }
    #pragma unroll
    for (int j = 0; j < 4; ++j) sc[j] *= 0.125f;

    float mx = fmaxf(fmaxf(sc[0], sc[1]), fmaxf(sc[2], sc[3]));
    mx = fmaxf(mx, __shfl_xor(mx, 1));
    mx = fmaxf(mx, __shfl_xor(mx, 2));
    float ex[4], s = 0.f;
    #pragma unroll
    for (int j = 0; j < 4; ++j) { ex[j] = __expf(sc[j] - mx); s += ex[j]; }
    s += __shfl_xor(s, 1);
    s += __shfl_xor(s, 2);
    const float inv = 1.f / s;
    #pragma unroll
    for (int j = 0; j < 4; ++j) sp[w][h * 16 + t0 + j] = ex[j] * inv;
    __syncthreads();

    const int dbase = (lane & 3) * 16;
    float o[16] = {};
    for (int t = 0; t < 16; ++t) {
        const float p = sp[w][h * 16 + t];
        const bf16x8 v0 = *(const bf16x8*)&sv[w][t * RS + dbase];
        const bf16x8 v1 = *(const bf16x8*)&sv[w][t * RS + dbase + 8];
        #pragma unroll
        for (int e = 0; e < 8; ++e) {
            o[e]     += p * bf2f(v0[e]);
            o[e + 8] += p * bf2f(v1[e]);
        }
    }
    bf16x8 ov0, ov1;
    #pragma unroll
    for (int e = 0; e < 8; ++e) { ov0[e] = f2bf(o[e]); ov1[e] = f2bf(o[e + 8]); }
    *(bf16x8*)(Z + tok * 1024 + lane * 16)     = ov0;
    *(bf16x8*)(Z + tok * 1024 + lane * 16 + 8) = ov1;
}

// ---------------------------------------------------------------------------
extern "C" void kernel_launch(void* const* d_in, const int* in_sizes, int n_in,
                              void* d_out, int out_size, void* d_ws, size_t ws_size,
                              hipStream_t stream) {
    const void* X = d_in[0];                   // [32768,1024] fp32 (detected)

    const long TOT = 32768;
    constexpr long WELEM = 1024 * 1024;

    char* ws   = (char*)d_ws;
    int*  flag = (int*)ws;
    short* Wqb = (short*)(ws + 256);           // [Wq|Wk|Wv|Wo|Xb] contiguous
    short* Wkb = Wqb + WELEM;
    short* Wvb = Wkb + WELEM;
    short* Wob = Wvb + WELEM;
    short* dyn = Wob + WELEM;

    const size_t fixed = 256 + 4 * WELEM * 2;
    long chunk = 256;
    const long tiers[4] = {32768, 8192, 2048, 512};
    for (int i = 0; i < 4; ++i)
        if (fixed + (size_t)6 * tiers[i] * 1024 * 2 <= ws_size) { chunk = tiers[i]; break; }

    short* Xb = dyn;                 // chunk*1024 bf16 (contiguous after Wob)
    short* Qb = Xb + chunk * 1024;
    short* Kb = Qb + chunk * 1024;
    short* Vb = Kb + chunk * 1024;
    short* Zb = Vb + chunk * 1024;

    detect_dtype<<<1, 256, 0, stream>>>((const unsigned*)X, flag);

    if (chunk == TOT) {
        convert_all<<<2048, 256, 0, stream>>>(X, d_in[1], d_in[2], d_in[3], d_in[4],
                                              Wqb, 4 * WELEM + TOT * 1024, flag);
        gemm_qkv256<<<dim3((TOT / 256) * 12), 256, 0, stream>>>(Xb, Wqb, Wkb, Wvb,
                                                                Qb, Kb, Vb);
        attn_mix<<<dim3(TOT / 4), 256, 0, stream>>>(Qb, Kb, Vb, Zb);
        gemm_out256<<<dim3((TOT / 256) * 4), 256, 0, stream>>>(Zb, Wob, d_out, 0, flag);
    } else {
        convert_all<<<512, 256, 0, stream>>>(X, d_in[1], d_in[2], d_in[3], d_in[4],
                                             Wqb, 4 * WELEM, flag);
        for (long t0 = 0; t0 < TOT; t0 += chunk) {
            convert_all<<<2048, 256, 0, stream>>>(
                (const void*)((const char*)X + (size_t)t0 * 1024 * 4),
                d_in[1], d_in[2], d_in[3], d_in[4],
                Xb - 4 * WELEM, 4 * WELEM + chunk * 1024, flag);
            gemm_qkv256<<<dim3((chunk / 256) * 12), 256, 0, stream>>>(Xb, Wqb, Wkb, Wvb,
                                                                      Qb, Kb, Vb);
            attn_mix<<<dim3(chunk / 4), 256, 0, stream>>>(Qb, Kb, Vb, Zb);
            gemm_out256<<<dim3((chunk / 256) * 4), 256, 0, stream>>>(Zb - t0 * 1024, Wob,
                                                                     d_out, t0, flag);
        }
    }
}